// Round 7
// baseline (201.057 us; speedup 1.0000x reference)
//
#include <hip/hip_runtime.h>

#define BATCH 1024
#define NANCH 3125
#define LAMB  5.0f
#define SPLIT 4
#define CHUNK ((NANCH + SPLIT - 1) / SPLIT)   // 782 (last chunk 779)
#define NBLK  (BATCH * SPLIT)                 // 4096
#define INV_B (1.0f / 1024.0f)

__device__ __forceinline__ float wave_red_f(float v) {
    #pragma unroll
    for (int o = 32; o > 0; o >>= 1) v += __shfl_down(v, o, 64);
    return v;
}

__device__ __forceinline__ float lse2(float2 c) {
    const float m = fmaxf(c.x, c.y);
    return m + __logf(1.f + __expf(-fabsf(c.x - c.y)));
}

__device__ __forceinline__ float sl1(float4 p, float4 t) {
    float s4 = 0.f, d, a;
    d = p.x - t.x; a = fabsf(d); s4 += (a < 1.f) ? 0.5f * d * d : a - 0.5f;
    d = p.y - t.y; a = fabsf(d); s4 += (a < 1.f) ? 0.5f * d * d : a - 0.5f;
    d = p.z - t.z; a = fabsf(d); s4 += (a < 1.f) ? 0.5f * d * d : a - 0.5f;
    d = p.w - t.w; a = fabsf(d); s4 += (a < 1.f) ? 0.5f * d * d : a - 0.5f;
    return s4 * 0.25f;
}

// grid = NBLK, block = 256. R6 streaming body + distributed epilogue:
//  - block (b,s) atomic-stores its 5 partials (AGENT scope, coherent point);
//  - per-batch acq_rel ticket elects the 4th finisher -> batch epilogue ->
//    fetch_add scaled contributions into 2 global scalars;
//  - global acq_rel ticket elects the overall last block -> writes out[0..2].
// No threadfence anywhere (R3 lesson), no second kernel launch.
__global__ __launch_bounds__(256) void fused_kernel(
    const float* __restrict__ c_pred,    // [B,N,2]
    const float* __restrict__ r_pred,    // [B,N,4]
    const float* __restrict__ r_target,  // [B,N,4]
    const int*   __restrict__ label,     // [B,N]
    float*       __restrict__ c_acc,     // [1] zeroed per launch
    float*       __restrict__ r_acc,     // [1] zeroed per launch
    unsigned*    __restrict__ gtick,     // [1] zeroed per launch
    unsigned*    __restrict__ btick,     // [BATCH] zeroed per launch
    float*       __restrict__ part,      // [BATCH][SPLIT][5], no zeroing needed
    float*       __restrict__ out)       // [3]
{
    const int blk = blockIdx.x;
    const int b   = blk / SPLIT;
    const int s   = blk % SPLIT;
    const int tid = threadIdx.x;

    const float2* c2 = (const float2*)(c_pred   + (size_t)b * NANCH * 2);
    const float4* rp = (const float4*)(r_pred   + (size_t)b * NANCH * 4);
    const float4* rt = (const float4*)(r_target + (size_t)b * NANCH * 4);
    const int*    lb = label + (size_t)b * NANCH;

    const int start = s * CHUNK;
    const int end   = min(start + CHUNK, NANCH);

    const int  i0 = start + tid;
    const int  i1 = i0 + 256;
    const int  i2 = i0 + 512;
    const int  i3 = i0 + 768;
    const bool v3 = (i3 < end);
    const int  j3 = v3 ? i3 : i0;

    // phase 1: independent label + c loads
    const int l0 = lb[i0];
    const int l1 = lb[i1];
    const int l2 = lb[i2];
    int       l3 = lb[j3];
    const float2 c0 = c2[i0];
    const float2 c1 = c2[i1];
    const float2 cc2 = c2[i2];
    const float2 c3 = c2[j3];
    if (!v3) l3 = -1;

    // phase 2: issue-only conditional r loads
    const bool p0 = (l0 == 1), p1 = (l1 == 1), p2 = (l2 == 1), p3 = (l3 == 1);
    float4 P0, T0, P1, T1, P2, T2, P3, T3;
    if (p0) { P0 = rp[i0]; T0 = rt[i0]; }
    if (p1) { P1 = rp[i1]; T1 = rt[i1]; }
    if (p2) { P2 = rp[i2]; T2 = rt[i2]; }
    if (p3) { P3 = rp[i3]; T3 = rt[i3]; }

    // phase 3: consume
    float cp, cn, sl = 0.f, pc, nc;

    const float e0 = lse2(c0), e1 = lse2(c1), e2 = lse2(cc2), e3 = lse2(c3);
    const bool n0 = (l0 == 0), n1 = (l1 == 0), n2 = (l2 == 0), n3 = (l3 == 0);

    pc = (p0 ? 1.f : 0.f) + (p1 ? 1.f : 0.f) + (p2 ? 1.f : 0.f) + (p3 ? 1.f : 0.f);
    nc = (n0 ? 1.f : 0.f) + (n1 ? 1.f : 0.f) + (n2 ? 1.f : 0.f) + (n3 ? 1.f : 0.f);
    cp = (p0 ? (e0 - c0.y) : 0.f) + (p1 ? (e1 - c1.y) : 0.f)
       + (p2 ? (e2 - cc2.y) : 0.f) + (p3 ? (e3 - c3.y) : 0.f);
    cn = (n0 ? (e0 - c0.x) : 0.f) + (n1 ? (e1 - c1.x) : 0.f)
       + (n2 ? (e2 - cc2.x) : 0.f) + (n3 ? (e3 - c3.x) : 0.f);

    if (p0) sl += sl1(P0, T0);
    if (p1) sl += sl1(P1, T1);
    if (p2) sl += sl1(P2, T2);
    if (p3) sl += sl1(P3, T3);

    // block reduction
    cp = wave_red_f(cp);
    cn = wave_red_f(cn);
    sl = wave_red_f(sl);
    pc = wave_red_f(pc);
    nc = wave_red_f(nc);

    __shared__ float sm[5][4];
    const int wid = tid >> 6, lane = tid & 63;
    if (lane == 0) {
        sm[0][wid] = cp; sm[1][wid] = cn; sm[2][wid] = sl;
        sm[3][wid] = pc; sm[4][wid] = nc;
    }
    __syncthreads();

    if (tid == 0) {
        float v[5];
        #pragma unroll
        for (int k = 0; k < 5; ++k) v[k] = sm[k][0] + sm[k][1] + sm[k][2] + sm[k][3];

        // publish my partials at the coherent point
        float* mine = part + ((size_t)b * SPLIT + s) * 5;
        #pragma unroll
        for (int k = 0; k < 5; ++k)
            __hip_atomic_store(&mine[k], v[k], __ATOMIC_RELAXED, __HIP_MEMORY_SCOPE_AGENT);

        // per-batch ticket: 4th finisher runs the batch epilogue
        const unsigned bo = __hip_atomic_fetch_add(&btick[b], 1u, __ATOMIC_ACQ_REL, __HIP_MEMORY_SCOPE_AGENT);
        if (bo == SPLIT - 1) {
            float tcp = v[0], tcn = v[1], tsl = v[2], tpc = v[3], tnc = v[4];
            #pragma unroll
            for (int ss = 0; ss < SPLIT; ++ss) {
                if (ss == s) continue;
                const float* o = part + ((size_t)b * SPLIT + ss) * 5;
                tcp += __hip_atomic_load(&o[0], __ATOMIC_RELAXED, __HIP_MEMORY_SCOPE_AGENT);
                tcn += __hip_atomic_load(&o[1], __ATOMIC_RELAXED, __HIP_MEMORY_SCOPE_AGENT);
                tsl += __hip_atomic_load(&o[2], __ATOMIC_RELAXED, __HIP_MEMORY_SCOPE_AGENT);
                tpc += __hip_atomic_load(&o[3], __ATOMIC_RELAXED, __HIP_MEMORY_SCOPE_AGENT);
                tnc += __hip_atomic_load(&o[4], __ATOMIC_RELAXED, __HIP_MEMORY_SCOPE_AGENT);
            }
            const bool  haspos   = (tpc > 0.5f);
            const float pos_mean = haspos ? tcp / tpc : 0.f;
            const float neg_mean = tcn / fmaxf(tnc, 1.f);
            const float c_contrib = (pos_mean + neg_mean) * 0.5f * INV_B;
            const float r_contrib = (haspos ? tsl / tpc : 0.f) * INV_B;

            __hip_atomic_fetch_add(c_acc, c_contrib, __ATOMIC_RELAXED, __HIP_MEMORY_SCOPE_AGENT);
            __hip_atomic_fetch_add(r_acc, r_contrib, __ATOMIC_RELAXED, __HIP_MEMORY_SCOPE_AGENT);

            // global ticket over completed batches: last one writes outputs
            const unsigned go = __hip_atomic_fetch_add(gtick, 1u, __ATOMIC_ACQ_REL, __HIP_MEMORY_SCOPE_AGENT);
            if (go == BATCH - 1) {
                const float c_loss = __hip_atomic_load(c_acc, __ATOMIC_ACQUIRE, __HIP_MEMORY_SCOPE_AGENT);
                const float r_loss = __hip_atomic_load(r_acc, __ATOMIC_ACQUIRE, __HIP_MEMORY_SCOPE_AGENT);
                out[0] = c_loss;
                out[1] = r_loss;
                out[2] = c_loss + LAMB * r_loss;
            }
        }
    }
}

extern "C" void kernel_launch(void* const* d_in, const int* in_sizes, int n_in,
                              void* d_out, int out_size, void* d_ws, size_t ws_size,
                              hipStream_t stream) {
    const float* c_pred   = (const float*)d_in[0];
    const float* r_pred   = (const float*)d_in[1];
    const float* r_target = (const float*)d_in[2];
    const int*   label    = (const int*)d_in[3];
    float*       out      = (float*)d_out;

    float*    c_acc = (float*)d_ws;                          // offset 0
    float*    r_acc = (float*)((char*)d_ws + 128);           // separate line
    unsigned* gtick = (unsigned*)((char*)d_ws + 256);        // separate line
    unsigned* btick = (unsigned*)((char*)d_ws + 512);        // 4 KiB
    float*    part  = (float*)((char*)d_ws + 8192);          // 80 KiB, not zeroed

    hipMemsetAsync(d_ws, 0, 4608, stream);                   // accs + tickets
    fused_kernel<<<NBLK, 256, 0, stream>>>(c_pred, r_pred, r_target, label,
                                           c_acc, r_acc, gtick, btick, part, out);
}

// Round 8
// 28.250 us; speedup vs baseline: 7.1171x; 7.1171x over previous
//
#include <hip/hip_runtime.h>

#define BATCH 1024
#define NANCH 3125
#define LAMB  5.0f
#define NBLK  (BATCH * 4)   // 4 blocks per batch row

__device__ __forceinline__ float wave_red_f(float v) {
    #pragma unroll
    for (int o = 32; o > 0; o >>= 1) v += __shfl_down(v, o, 64);
    return v;
}

__device__ __forceinline__ float lse2(float cx, float cy) {
    const float m = fmaxf(cx, cy);
    return m + __logf(1.f + __expf(-fabsf(cx - cy)));
}

__device__ __forceinline__ float sl1(float4 p, float4 t) {
    float s4 = 0.f, d, a;
    d = p.x - t.x; a = fabsf(d); s4 += (a < 1.f) ? 0.5f * d * d : a - 0.5f;
    d = p.y - t.y; a = fabsf(d); s4 += (a < 1.f) ? 0.5f * d * d : a - 0.5f;
    d = p.z - t.z; a = fabsf(d); s4 += (a < 1.f) ? 0.5f * d * d : a - 0.5f;
    d = p.w - t.w; a = fabsf(d); s4 += (a < 1.f) ? 0.5f * d * d : a - 0.5f;
    return s4 * 0.25f;
}

// grid = NBLK, block = 256. Each thread handles ONE aligned group of 4
// consecutive anchors: 1x int4 label + 2x float4 c + <=8 conditional float4 r
// = 11 VMEM instructions per 4 anchors (vs 16 in the strided layout).
// Row base b*3125 === b (mod 4), so groups start at align0=(4-b&3)&3 which
// 16B-aligns BOTH the int4 label load and the float4 c loads. The <=5
// head/tail anchors per row run a scalar path on spare thread slots.
// Plain stores + second kernel; NO device-scope atomics/fences in the hot
// path (R3/R4/R7 lesson: they trigger the XCD coherence slow path, 2-7x).
__global__ __launch_bounds__(256) void partial_kernel(
    const float* __restrict__ c_pred,    // [B,N,2]
    const float* __restrict__ r_pred,    // [B,N,4]
    const float* __restrict__ r_target,  // [B,N,4]
    const int*   __restrict__ label,     // [B,N]
    float*       __restrict__ partial)   // [NBLK, 5]
{
    const int blk = blockIdx.x;
    const int b   = blk >> 2;
    const int s   = blk & 3;
    const int tid = threadIdx.x;
    const int u   = (s << 8) | tid;              // 0..1023: group slot in row

    const int align0  = (4 - (b & 3)) & 3;       // first 16B-aligned anchor
    const int ngroups = (NANCH - align0) >> 2;   // 780 or 781
    const int ntail   = NANCH - align0 - (ngroups << 2);

    const float*  crow = c_pred + (size_t)b * (NANCH * 2);
    const float4* rp   = (const float4*)(r_pred   + (size_t)b * NANCH * 4);
    const float4* rt   = (const float4*)(r_target + (size_t)b * NANCH * 4);
    const int*    lb   = label + (size_t)b * NANCH;

    float cp = 0.f, cn = 0.f, sl = 0.f, pc = 0.f, nc = 0.f;

    if (u < ngroups) {
        const int a = align0 + (u << 2);

        // phase 1: wide label + c loads (3 VMEM, independent, in flight together)
        const int4   L   = *(const int4*)(lb + a);
        const float4 C01 = *(const float4*)(crow + 2 * a);
        const float4 C23 = *(const float4*)(crow + 2 * a + 4);

        // phase 2: issue-only conditional r loads
        const bool p0 = (L.x == 1), p1 = (L.y == 1), p2 = (L.z == 1), p3 = (L.w == 1);
        float4 P0, T0, P1, T1, P2, T2, P3, T3;
        if (p0) { P0 = rp[a];     T0 = rt[a];     }
        if (p1) { P1 = rp[a + 1]; T1 = rt[a + 1]; }
        if (p2) { P2 = rp[a + 2]; T2 = rt[a + 2]; }
        if (p3) { P3 = rp[a + 3]; T3 = rt[a + 3]; }

        // phase 3: consume
        const float e0 = lse2(C01.x, C01.y), e1 = lse2(C01.z, C01.w);
        const float e2 = lse2(C23.x, C23.y), e3 = lse2(C23.z, C23.w);
        const bool n0 = (L.x == 0), n1 = (L.y == 0), n2 = (L.z == 0), n3 = (L.w == 0);

        pc = (p0 ? 1.f : 0.f) + (p1 ? 1.f : 0.f) + (p2 ? 1.f : 0.f) + (p3 ? 1.f : 0.f);
        nc = (n0 ? 1.f : 0.f) + (n1 ? 1.f : 0.f) + (n2 ? 1.f : 0.f) + (n3 ? 1.f : 0.f);
        cp = (p0 ? (e0 - C01.y) : 0.f) + (p1 ? (e1 - C01.w) : 0.f)
           + (p2 ? (e2 - C23.y) : 0.f) + (p3 ? (e3 - C23.w) : 0.f);
        cn = (n0 ? (e0 - C01.x) : 0.f) + (n1 ? (e1 - C01.z) : 0.f)
           + (n2 ? (e2 - C23.x) : 0.f) + (n3 ? (e3 - C23.z) : 0.f);

        if (p0) sl += sl1(P0, T0);
        if (p1) sl += sl1(P1, T1);
        if (p2) sl += sl1(P2, T2);
        if (p3) sl += sl1(P3, T3);
    } else {
        // scalar path for the <=5 unaligned head/tail anchors of this row
        const int k = u - ngroups;
        const int nextra = align0 + ntail;
        if (k < nextra) {
            const int a = (k < align0) ? k
                        : (align0 + (ngroups << 2) + (k - align0));
            const int   l  = lb[a];
            const float cx = crow[2 * a], cy = crow[2 * a + 1];
            const float e  = lse2(cx, cy);
            if (l == 1) {
                pc = 1.f; cp = e - cy;
                sl = sl1(rp[a], rt[a]);
            } else if (l == 0) {
                nc = 1.f; cn = e - cx;
            }
        }
    }

    // block reduction
    cp = wave_red_f(cp);
    cn = wave_red_f(cn);
    sl = wave_red_f(sl);
    pc = wave_red_f(pc);
    nc = wave_red_f(nc);

    __shared__ float sm[5][4];
    const int wid = tid >> 6, lane = tid & 63;
    if (lane == 0) {
        sm[0][wid] = cp; sm[1][wid] = cn; sm[2][wid] = sl;
        sm[3][wid] = pc; sm[4][wid] = nc;
    }
    __syncthreads();
    if (tid < 5) {
        const int k = tid;
        partial[(size_t)blk * 5 + k] = sm[k][0] + sm[k][1] + sm[k][2] + sm[k][3];
    }
}

// grid = 1, block = 512. Combine 4 partials per batch, per-batch epilogue,
// reduce over batches, emit (c_loss, r_loss, t_loss).
__global__ __launch_bounds__(512) void finalize_kernel(
    const float* __restrict__ partial,   // [NBLK, 5]
    float*       __restrict__ out)       // [3]
{
    const int tid = threadIdx.x;
    float csum = 0.f, rsum = 0.f;

    for (int b = tid; b < BATCH; b += 512) {
        float cp = 0.f, cn = 0.f, sl = 0.f, pc = 0.f, nc = 0.f;
        #pragma unroll
        for (int s = 0; s < 4; ++s) {
            const float* p = partial + ((size_t)b * 4 + s) * 5;
            cp += p[0]; cn += p[1]; sl += p[2]; pc += p[3]; nc += p[4];
        }
        const bool haspos = (pc > 0.5f);
        const float pos_mean = haspos ? cp / pc : 0.f;
        const float neg_mean = cn / fmaxf(nc, 1.f);
        csum += (pos_mean + neg_mean) * 0.5f;
        rsum += haspos ? sl / pc : 0.f;
    }

    csum = wave_red_f(csum);
    rsum = wave_red_f(rsum);

    __shared__ float s_c[8], s_r[8];
    const int wid = tid >> 6, lane = tid & 63;
    if (lane == 0) { s_c[wid] = csum; s_r[wid] = rsum; }
    __syncthreads();
    if (tid == 0) {
        float cs = 0.f, rs = 0.f;
        #pragma unroll
        for (int w = 0; w < 8; ++w) { cs += s_c[w]; rs += s_r[w]; }
        const float c_loss = cs / (float)BATCH;
        const float r_loss = rs / (float)BATCH;
        out[0] = c_loss;
        out[1] = r_loss;
        out[2] = c_loss + LAMB * r_loss;
    }
}

extern "C" void kernel_launch(void* const* d_in, const int* in_sizes, int n_in,
                              void* d_out, int out_size, void* d_ws, size_t ws_size,
                              hipStream_t stream) {
    const float* c_pred   = (const float*)d_in[0];
    const float* r_pred   = (const float*)d_in[1];
    const float* r_target = (const float*)d_in[2];
    const int*   label    = (const int*)d_in[3];
    float*       out      = (float*)d_out;
    float*       partial  = (float*)d_ws;   // NBLK*5 floats = 80 KiB

    partial_kernel<<<NBLK, 256, 0, stream>>>(c_pred, r_pred, r_target, label, partial);
    finalize_kernel<<<1, 512, 0, stream>>>(partial, out);
}